// Round 1
// baseline (297.393 us; speedup 1.0000x reference)
//
#include <hip/hip_runtime.h>

#define ALPHA 0.25f
#define GAMMA_UNUSED 2.0f
#define CLS_LO 1.0e-4f
#define CLS_HI 0.9999f   // float(1.0 - 0.0001)

// workspace layout per image (floats): counts[M], sums[3*M], sumsq[M], cls_sum, reg_sum, num_pos
// stride = 5*M + 3

__device__ __forceinline__ float smooth_l1(float d) {
    d = fabsf(d);
    return (d <= (1.0f / 9.0f)) ? (4.5f * d * d) : (d - (0.5f / 9.0f));
}

__global__ void __launch_bounds__(256)
det_main_kernel(const float* __restrict__ cls,
                const float* __restrict__ reg,
                const float* __restrict__ anc,
                const float* __restrict__ ann,
                float* __restrict__ ws,
                int A, int C, int M)
{
    const int b   = blockIdx.y;
    const int tid = threadIdx.x;
    const int a   = blockIdx.x * blockDim.x + tid;
    const int wsStride = 5 * M + 3;

    __shared__ float sb[5 * 64];            // M <= 64 boxes, 5 floats each
    __shared__ float s_cnt[64], s_sx[64], s_sy[64], s_sz[64], s_sq[64];
    __shared__ float s_scal[3];             // cls_sum, reg_sum, num_pos

    for (int i = tid; i < M * 5; i += blockDim.x)
        sb[i] = ann[(size_t)b * M * 5 + i];
    if (tid < M) { s_cnt[tid] = 0.f; s_sx[tid] = 0.f; s_sy[tid] = 0.f; s_sz[tid] = 0.f; s_sq[tid] = 0.f; }
    if (tid < 3) s_scal[tid] = 0.f;
    __syncthreads();

    float contrib_cls = 0.f, contrib_reg = 0.f, contrib_np = 0.f;

    if (a < A) {
        // anchor in yx layout: [y1, x1, y2, x2]
        float4 av = ((const float4*)anc)[a];
        const float ay1 = av.x, ax1 = av.y, ay2 = av.z, ax2 = av.w;
        const float aw  = ax2 - ax1;
        const float ah  = ay2 - ay1;
        const float acx = ax1 + 0.5f * aw;
        const float acy = ay1 + 0.5f * ah;
        const float area_a = ah * aw;

        float best = -1.0f;
        int   bj   = 0;
        for (int j = 0; j < M; j++) {
            const float bx1 = sb[j * 5 + 0];
            const float by1 = sb[j * 5 + 1];
            const float bx2 = sb[j * 5 + 2];
            const float by2 = sb[j * 5 + 3];
            float iw = fminf(ax2, bx2) - fmaxf(ax1, bx1); iw = fmaxf(iw, 0.f);
            float ih = fminf(ay2, by2) - fmaxf(ay1, by1); ih = fmaxf(ih, 0.f);
            const float inter = iw * ih;
            const float ua = fmaxf(area_a + (bx2 - bx1) * (by2 - by1) - inter, 1e-8f);
            const float iou = inter / ua;
            if (iou > best) { best = iou; bj = j; }   // strict >: first-max, matches jnp.argmax
        }
        const bool pos = best >= 0.5f;
        const bool neg = best < 0.4f;

        if (pos || neg) {
            // focal loss: uniform negative-term loop (+ positive-class fixup)
            const float* cbase = cls + ((size_t)b * A + a) * (size_t)C;
            const float4* cp = (const float4*)cbase;
            float acc = 0.f;
            const int nq = C >> 2;
            for (int q = 0; q < nq; q++) {
                float4 v = cp[q];
                float p;
                p = fminf(fmaxf(v.x, CLS_LO), CLS_HI); acc += 0.75f * p * p * (-__logf(1.f - p));
                p = fminf(fmaxf(v.y, CLS_LO), CLS_HI); acc += 0.75f * p * p * (-__logf(1.f - p));
                p = fminf(fmaxf(v.z, CLS_LO), CLS_HI); acc += 0.75f * p * p * (-__logf(1.f - p));
                p = fminf(fmaxf(v.w, CLS_LO), CLS_HI); acc += 0.75f * p * p * (-__logf(1.f - p));
            }
            for (int c = nq << 2; c < C; c++) {
                float p = fminf(fmaxf(cbase[c], CLS_LO), CLS_HI);
                acc += 0.75f * p * p * (-__logf(1.f - p));
            }
            if (pos) {
                const int L = (int)sb[bj * 5 + 4];
                float p = fminf(fmaxf(cbase[L], CLS_LO), CLS_HI);
                acc -= 0.75f * p * p * (-__logf(1.f - p));
                acc += 0.25f * (1.f - p) * (1.f - p) * (-__logf(p));
            }
            contrib_cls = acc;
        }

        if (pos) {
            contrib_np = 1.0f;
            const float* rp = reg + ((size_t)b * A + a) * 7;
            const float r0 = rp[0], r1 = rp[1], r2 = rp[2], r3 = rp[3];
            const float e0 = rp[4], e1 = rp[5], e2 = rp[6];

            const float bx1 = sb[bj * 5 + 0];
            const float by1 = sb[bj * 5 + 1];
            const float bx2 = sb[bj * 5 + 2];
            const float by2 = sb[bj * 5 + 3];
            float gw = bx2 - bx1;
            float gh = by2 - by1;
            const float gcx = bx1 + 0.5f * gw;
            const float gcy = by1 + 0.5f * gh;
            gw = fmaxf(gw, 1.f);
            gh = fmaxf(gh, 1.f);
            const float t0 = (gcy - acy) / ah;
            const float t1 = (gcx - acx) / aw;
            const float t2 = logf(gh / ah);
            const float t3 = logf(gw / aw);
            contrib_reg = smooth_l1(t0 - r0) + smooth_l1(t1 - r1) +
                          smooth_l1(t2 - r2) + smooth_l1(t3 - r3);

            atomicAdd(&s_cnt[bj], 1.f);
            atomicAdd(&s_sx[bj], e0);
            atomicAdd(&s_sy[bj], e1);
            atomicAdd(&s_sz[bj], e2);
            atomicAdd(&s_sq[bj], e0 * e0 + e1 * e1 + e2 * e2);
        }
    }

    // wave64 reduction of scalars, then one LDS atomic per wave
    for (int off = 32; off > 0; off >>= 1) {
        contrib_cls += __shfl_down(contrib_cls, off, 64);
        contrib_reg += __shfl_down(contrib_reg, off, 64);
        contrib_np  += __shfl_down(contrib_np,  off, 64);
    }
    if ((tid & 63) == 0) {
        atomicAdd(&s_scal[0], contrib_cls);
        atomicAdd(&s_scal[1], contrib_reg);
        atomicAdd(&s_scal[2], contrib_np);
    }
    __syncthreads();

    float* wsb = ws + (size_t)b * wsStride;
    if (tid < M) {
        const float c = s_cnt[tid];
        if (c != 0.f) {   // only blocks containing positive anchors hit global atomics
            atomicAdd(&wsb[tid], c);
            atomicAdd(&wsb[M + 3 * tid + 0], s_sx[tid]);
            atomicAdd(&wsb[M + 3 * tid + 1], s_sy[tid]);
            atomicAdd(&wsb[M + 3 * tid + 2], s_sz[tid]);
            atomicAdd(&wsb[4 * M + tid], s_sq[tid]);
        }
    }
    if (tid == 0) {
        atomicAdd(&wsb[5 * M + 0], s_scal[0]);
        atomicAdd(&wsb[5 * M + 1], s_scal[1]);
        atomicAdd(&wsb[5 * M + 2], s_scal[2]);
    }
}

__global__ void det_final_kernel(const float* __restrict__ ws,
                                 float* __restrict__ out,
                                 int B, int M)
{
    const int t = threadIdx.x;
    const int wsStride = 5 * M + 3;
    __shared__ float s_emb[8];
    if (t < B) s_emb[t] = 0.f;
    __syncthreads();

    if (t < B * M) {
        const int b = t / M;
        const int m = t - b * M;
        const float* wsb = ws + (size_t)b * wsStride;
        const float c = wsb[m];
        float mx = 0.f, my = 0.f, mz = 0.f, pa = 0.f;
        if (c > 0.f) {
            mx = wsb[M + 3 * m + 0] / c;
            my = wsb[M + 3 * m + 1] / c;
            mz = wsb[M + 3 * m + 2] / c;
            // sum |e - mean|^2 = sum|e|^2 - c*|mean|^2
            const float sq = wsb[4 * M + m] - c * (mx * mx + my * my + mz * mz);
            pa = sq / fmaxf(c * 3.f, 1.f);
        }
        out[3 + (size_t)(b * M + m) * 3 + 0] = mx;
        out[3 + (size_t)(b * M + m) * 3 + 1] = my;
        out[3 + (size_t)(b * M + m) * 3 + 2] = mz;
        atomicAdd(&s_emb[b], pa);
    }
    __syncthreads();

    if (t == 0) {
        float cl = 0.f, rl = 0.f, el = 0.f;
        for (int b = 0; b < B; b++) {
            const float* wsb = ws + (size_t)b * wsStride;
            const float np = wsb[5 * M + 2];
            cl += wsb[5 * M + 0] / fmaxf(np, 1.f);
            rl += wsb[5 * M + 1] / fmaxf(4.f * np, 1.f);
            el += s_emb[b] / (float)M;
        }
        const float invB = 1.f / (float)B;
        out[0] = cl * invB;
        out[1] = rl * invB * 50.f;
        out[2] = el * invB;
    }
}

extern "C" void kernel_launch(void* const* d_in, const int* in_sizes, int n_in,
                              void* d_out, int out_size, void* d_ws, size_t ws_size,
                              hipStream_t stream) {
    const float* cls = (const float*)d_in[0];
    const float* reg = (const float*)d_in[1];
    const float* anc = (const float*)d_in[2];
    const float* ann = (const float*)d_in[3];
    float* out = (float*)d_out;
    float* ws  = (float*)d_ws;

    const int A = in_sizes[2] / 4;               // anchors: (1, A, 4)
    const int B = in_sizes[1] / (A * 7);         // regressions: (B, A, 7)
    const int C = in_sizes[0] / (B * A);         // classifications: (B, A, C)
    const int M = in_sizes[3] / (B * 5);         // annotations: (B, M, 5)
    const int wsStride = 5 * M + 3;

    hipMemsetAsync(ws, 0, (size_t)B * wsStride * sizeof(float), stream);

    dim3 grid((A + 255) / 256, B);
    det_main_kernel<<<grid, 256, 0, stream>>>(cls, reg, anc, ann, ws, A, C, M);
    det_final_kernel<<<1, 256, 0, stream>>>(ws, out, B, M);
}

// Round 2
// 235.115 us; speedup vs baseline: 1.2649x; 1.2649x over previous
//
#include <hip/hip_runtime.h>

#define ALPHA 0.25f
#define CLS_LO 1.0e-4f
#define CLS_HI 0.9999f   // float(1.0 - 0.0001)

// workspace layout per image (floats): counts[M], sums[3*M], sumsq[M], cls_sum, reg_sum, num_pos
// stride = 5*M + 3

__device__ __forceinline__ float smooth_l1(float d) {
    d = fabsf(d);
    return (d <= (1.0f / 9.0f)) ? (4.5f * d * d) : (d - (0.5f / 9.0f));
}

__device__ __forceinline__ float neg_focal(float p) {
    // p pre-clamped. alpha=1-0.25, gamma=2: (1-a)*p^2 * -log(1-p)
    return 0.75f * p * p * (-__logf(1.0f - p));
}

__global__ void __launch_bounds__(256)
det_main_kernel(const float* __restrict__ cls,
                const float* __restrict__ reg,
                const float* __restrict__ anc,
                const float* __restrict__ ann,
                float* __restrict__ ws,
                int A, int C, int M)
{
    const int b   = blockIdx.y;
    const int tid = threadIdx.x;
    const int a0  = blockIdx.x * 256;
    const int a   = a0 + tid;
    const int wsStride = 5 * M + 3;

    __shared__ float sb[5 * 64];            // M <= 64 boxes, 5 floats each
    __shared__ float s_cnt[64], s_sx[64], s_sy[64], s_sz[64], s_sq[64];
    __shared__ float s_scal[3];             // cls_sum, reg_sum, num_pos
    __shared__ float s_maskf[256];          // per-local-anchor: 1.0 if (pos||neg), else 0.0

    for (int i = tid; i < M * 5; i += 256)
        sb[i] = ann[(size_t)b * M * 5 + i];
    if (tid < M) { s_cnt[tid] = 0.f; s_sx[tid] = 0.f; s_sy[tid] = 0.f; s_sz[tid] = 0.f; s_sq[tid] = 0.f; }
    if (tid < 3) s_scal[tid] = 0.f;
    s_maskf[tid] = 0.f;
    __syncthreads();

    float contrib_cls = 0.f, contrib_reg = 0.f, contrib_np = 0.f;

    // ---------------- phase 1: IoU assignment + rare pos-anchor work ----------------
    if (a < A) {
        // anchor in yx layout: [y1, x1, y2, x2]
        float4 av = ((const float4*)anc)[a];
        const float ay1 = av.x, ax1 = av.y, ay2 = av.z, ax2 = av.w;
        const float aw  = ax2 - ax1;
        const float ah  = ay2 - ay1;
        const float acx = ax1 + 0.5f * aw;
        const float acy = ay1 + 0.5f * ah;
        const float area_a = ah * aw;

        float best = -1.0f;
        int   bj   = 0;
        for (int j = 0; j < M; j++) {
            const float bx1 = sb[j * 5 + 0];
            const float by1 = sb[j * 5 + 1];
            const float bx2 = sb[j * 5 + 2];
            const float by2 = sb[j * 5 + 3];
            float iw = fminf(ax2, bx2) - fmaxf(ax1, bx1); iw = fmaxf(iw, 0.f);
            float ih = fminf(ay2, by2) - fmaxf(ay1, by1); ih = fmaxf(ih, 0.f);
            const float inter = iw * ih;
            const float ua = fmaxf(area_a + (bx2 - bx1) * (by2 - by1) - inter, 1e-8f);
            const float iou = inter / ua;
            if (iou > best) { best = iou; bj = j; }   // strict >: first-max, matches jnp.argmax
        }
        const bool pos = best >= 0.5f;
        const bool neg = best < 0.4f;
        s_maskf[tid] = (pos || neg) ? 1.0f : 0.0f;

        if (pos) {
            contrib_np = 1.0f;

            // focal fixup at the assigned class: replace the uniform negative term
            // (added for every class in phase 2) with the positive term.
            const float* cbase = cls + ((size_t)b * A + a) * (size_t)C;
            const int L = (int)sb[bj * 5 + 4];
            const float p = fminf(fmaxf(cbase[L], CLS_LO), CLS_HI);
            contrib_cls = 0.25f * (1.f - p) * (1.f - p) * (-__logf(p)) - neg_focal(p);

            const float* rp = reg + ((size_t)b * A + a) * 7;
            const float r0 = rp[0], r1 = rp[1], r2 = rp[2], r3 = rp[3];
            const float e0 = rp[4], e1 = rp[5], e2 = rp[6];

            const float bx1 = sb[bj * 5 + 0];
            const float by1 = sb[bj * 5 + 1];
            const float bx2 = sb[bj * 5 + 2];
            const float by2 = sb[bj * 5 + 3];
            float gw = bx2 - bx1;
            float gh = by2 - by1;
            const float gcx = bx1 + 0.5f * gw;
            const float gcy = by1 + 0.5f * gh;
            gw = fmaxf(gw, 1.f);
            gh = fmaxf(gh, 1.f);
            const float t0 = (gcy - acy) / ah;
            const float t1 = (gcx - acx) / aw;
            const float t2 = logf(gh / ah);
            const float t3 = logf(gw / aw);
            contrib_reg = smooth_l1(t0 - r0) + smooth_l1(t1 - r1) +
                          smooth_l1(t2 - r2) + smooth_l1(t3 - r3);

            atomicAdd(&s_cnt[bj], 1.f);
            atomicAdd(&s_sx[bj], e0);
            atomicAdd(&s_sy[bj], e1);
            atomicAdd(&s_sz[bj], e2);
            atomicAdd(&s_sq[bj], e0 * e0 + e1 * e1 + e2 * e2);
        }
    }
    __syncthreads();

    // ---------------- phase 2: coalesced focal sweep over the block's cls tile ----------------
    {
        const int nA = min(256, A - a0);              // anchors in this block
        const int n_elem = nA * C;                    // multiple of 4 (C=80)
        const float4* tile = (const float4*)(cls + ((size_t)b * A + a0) * (size_t)C);
        float acc = 0.f;
        for (int e4 = tid; e4 * 4 < n_elem; e4 += 256) {
            const float4 v = tile[e4];
            const unsigned e = (unsigned)(e4 * 4);
            // local-anchor index = e/80 via magic multiply (exact for e < 2^20 here)
            const unsigned i0 = (e * 52429u) >> 22;
            const unsigned i1 = ((e + 1u) * 52429u) >> 22;
            const unsigned i2 = ((e + 2u) * 52429u) >> 22;
            const unsigned i3 = ((e + 3u) * 52429u) >> 22;
            float p;
            p = fminf(fmaxf(v.x, CLS_LO), CLS_HI); acc += s_maskf[i0] * neg_focal(p);
            p = fminf(fmaxf(v.y, CLS_LO), CLS_HI); acc += s_maskf[i1] * neg_focal(p);
            p = fminf(fmaxf(v.z, CLS_LO), CLS_HI); acc += s_maskf[i2] * neg_focal(p);
            p = fminf(fmaxf(v.w, CLS_LO), CLS_HI); acc += s_maskf[i3] * neg_focal(p);
        }
        contrib_cls += acc;
    }

    // wave64 reduction of scalars, then one LDS atomic per wave
    for (int off = 32; off > 0; off >>= 1) {
        contrib_cls += __shfl_down(contrib_cls, off, 64);
        contrib_reg += __shfl_down(contrib_reg, off, 64);
        contrib_np  += __shfl_down(contrib_np,  off, 64);
    }
    if ((tid & 63) == 0) {
        atomicAdd(&s_scal[0], contrib_cls);
        atomicAdd(&s_scal[1], contrib_reg);
        atomicAdd(&s_scal[2], contrib_np);
    }
    __syncthreads();

    float* wsb = ws + (size_t)b * wsStride;
    if (tid < M) {
        const float c = s_cnt[tid];
        if (c != 0.f) {   // only blocks containing positive anchors hit global atomics
            atomicAdd(&wsb[tid], c);
            atomicAdd(&wsb[M + 3 * tid + 0], s_sx[tid]);
            atomicAdd(&wsb[M + 3 * tid + 1], s_sy[tid]);
            atomicAdd(&wsb[M + 3 * tid + 2], s_sz[tid]);
            atomicAdd(&wsb[4 * M + tid], s_sq[tid]);
        }
    }
    if (tid == 0) {
        atomicAdd(&wsb[5 * M + 0], s_scal[0]);
        atomicAdd(&wsb[5 * M + 1], s_scal[1]);
        atomicAdd(&wsb[5 * M + 2], s_scal[2]);
    }
}

__global__ void det_final_kernel(const float* __restrict__ ws,
                                 float* __restrict__ out,
                                 int B, int M)
{
    const int t = threadIdx.x;
    const int wsStride = 5 * M + 3;
    __shared__ float s_emb[8];
    if (t < B) s_emb[t] = 0.f;
    __syncthreads();

    if (t < B * M) {
        const int b = t / M;
        const int m = t - b * M;
        const float* wsb = ws + (size_t)b * wsStride;
        const float c = wsb[m];
        float mx = 0.f, my = 0.f, mz = 0.f, pa = 0.f;
        if (c > 0.f) {
            mx = wsb[M + 3 * m + 0] / c;
            my = wsb[M + 3 * m + 1] / c;
            mz = wsb[M + 3 * m + 2] / c;
            // sum |e - mean|^2 = sum|e|^2 - c*|mean|^2
            const float sq = wsb[4 * M + m] - c * (mx * mx + my * my + mz * mz);
            pa = sq / fmaxf(c * 3.f, 1.f);
        }
        out[3 + (size_t)(b * M + m) * 3 + 0] = mx;
        out[3 + (size_t)(b * M + m) * 3 + 1] = my;
        out[3 + (size_t)(b * M + m) * 3 + 2] = mz;
        atomicAdd(&s_emb[b], pa);
    }
    __syncthreads();

    if (t == 0) {
        float cl = 0.f, rl = 0.f, el = 0.f;
        for (int b = 0; b < B; b++) {
            const float* wsb = ws + (size_t)b * wsStride;
            const float np = wsb[5 * M + 2];
            cl += wsb[5 * M + 0] / fmaxf(np, 1.f);
            rl += wsb[5 * M + 1] / fmaxf(4.f * np, 1.f);
            el += s_emb[b] / (float)M;
        }
        const float invB = 1.f / (float)B;
        out[0] = cl * invB;
        out[1] = rl * invB * 50.f;
        out[2] = el * invB;
    }
}

extern "C" void kernel_launch(void* const* d_in, const int* in_sizes, int n_in,
                              void* d_out, int out_size, void* d_ws, size_t ws_size,
                              hipStream_t stream) {
    const float* cls = (const float*)d_in[0];
    const float* reg = (const float*)d_in[1];
    const float* anc = (const float*)d_in[2];
    const float* ann = (const float*)d_in[3];
    float* out = (float*)d_out;
    float* ws  = (float*)d_ws;

    const int A = in_sizes[2] / 4;               // anchors: (1, A, 4)
    const int B = in_sizes[1] / (A * 7);         // regressions: (B, A, 7)
    const int C = in_sizes[0] / (B * A);         // classifications: (B, A, C)
    const int M = in_sizes[3] / (B * 5);         // annotations: (B, M, 5)
    const int wsStride = 5 * M + 3;

    hipMemsetAsync(ws, 0, (size_t)B * wsStride * sizeof(float), stream);

    dim3 grid((A + 255) / 256, B);
    det_main_kernel<<<grid, 256, 0, stream>>>(cls, reg, anc, ann, ws, A, C, M);
    det_final_kernel<<<1, 256, 0, stream>>>(ws, out, B, M);
}

// Round 3
// 224.941 us; speedup vs baseline: 1.3221x; 1.0452x over previous
//
#include <hip/hip_runtime.h>

#define CLS_LO 1.0e-4f
#define CLS_HI 0.9999f   // float(1.0 - 0.0001)

// ws layout per image (floats): counts[M] | sums[3M] | sumsq[M] | blockScalars[3*NB]
// stride S = 5*M + 3*NB. Only the first 5*M need zeroing; we memset the whole thing.

__device__ __forceinline__ float smooth_l1(float d) {
    d = fabsf(d);
    return (d <= (1.0f / 9.0f)) ? (4.5f * d * d) : (d - (0.5f / 9.0f));
}

__global__ void __launch_bounds__(256)
det_main_kernel(const float* __restrict__ cls,
                const float* __restrict__ reg,
                const float* __restrict__ anc,
                const float* __restrict__ ann,
                float* __restrict__ ws,
                int A, int C, int M, int NB)
{
    const int b   = blockIdx.y;
    const int tid = threadIdx.x;
    const int a0  = blockIdx.x * 256;
    const int a   = a0 + tid;
    const int S   = 5 * M + 3 * NB;

    __shared__ float sb[5 * 64];            // M <= 64 boxes, 5 floats each
    __shared__ float s_cnt[64], s_sx[64], s_sy[64], s_sz[64], s_sq[64];
    __shared__ float s_maskf[256];          // 1.0 if anchor contributes neg focal term

    for (int i = tid; i < M * 5; i += 256)
        sb[i] = ann[(size_t)b * M * 5 + i];
    if (tid < M) { s_cnt[tid] = 0.f; s_sx[tid] = 0.f; s_sy[tid] = 0.f; s_sz[tid] = 0.f; s_sq[tid] = 0.f; }
    s_maskf[tid] = 0.f;
    __syncthreads();

    float contrib_cls = 0.f, contrib_reg = 0.f, contrib_np = 0.f;

    // ---------------- phase 1: IoU assignment + rare pos-anchor work ----------------
    if (a < A) {
        float4 av = ((const float4*)anc)[a];       // yx layout: [y1, x1, y2, x2]
        const float ay1 = av.x, ax1 = av.y, ay2 = av.z, ax2 = av.w;
        const float aw  = ax2 - ax1;
        const float ah  = ay2 - ay1;
        const float acx = ax1 + 0.5f * aw;
        const float acy = ay1 + 0.5f * ah;
        const float area_a = ah * aw;

        float best = -1.0f;
        int   bj   = 0;
#define IOU_BODY(j)                                                              \
        {                                                                        \
            const float bx1 = sb[(j) * 5 + 0];                                   \
            const float by1 = sb[(j) * 5 + 1];                                   \
            const float bx2 = sb[(j) * 5 + 2];                                   \
            const float by2 = sb[(j) * 5 + 3];                                   \
            float iw = fminf(ax2, bx2) - fmaxf(ax1, bx1); iw = fmaxf(iw, 0.f);   \
            float ih = fminf(ay2, by2) - fmaxf(ay1, by1); ih = fmaxf(ih, 0.f);   \
            const float inter = iw * ih;                                         \
            const float ua = fmaxf(area_a + (bx2 - bx1) * (by2 - by1) - inter,   \
                                   1e-8f);                                       \
            const float iou = inter / ua;                                        \
            if (iou > best) { best = iou; bj = (j); }                            \
        }
        if (M == 32) {
            #pragma unroll
            for (int j = 0; j < 32; j++) IOU_BODY(j)
        } else {
            for (int j = 0; j < M; j++) IOU_BODY(j)
        }
#undef IOU_BODY
        const bool pos = best >= 0.5f;
        const bool neg = best < 0.4f;
        s_maskf[tid] = (pos || neg) ? 1.0f : 0.0f;

        if (pos) {
            contrib_np = 1.0f;

            // focal fixup at the assigned class: phase 2 adds the uniform negative
            // term for every class; swap in the positive term at L.
            const float* cbase = cls + ((size_t)b * A + a) * (size_t)C;
            const int L = (int)sb[bj * 5 + 4];
            const float p = fminf(fmaxf(cbase[L], CLS_LO), CLS_HI);
            contrib_cls = 0.25f * (1.f - p) * (1.f - p) * (-__logf(p))
                        - 0.75f * p * p * (-__logf(1.f - p));

            const float* rp = reg + ((size_t)b * A + a) * 7;
            const float r0 = rp[0], r1 = rp[1], r2 = rp[2], r3 = rp[3];
            const float e0 = rp[4], e1 = rp[5], e2 = rp[6];

            const float bx1 = sb[bj * 5 + 0];
            const float by1 = sb[bj * 5 + 1];
            const float bx2 = sb[bj * 5 + 2];
            const float by2 = sb[bj * 5 + 3];
            float gw = bx2 - bx1;
            float gh = by2 - by1;
            const float gcx = bx1 + 0.5f * gw;
            const float gcy = by1 + 0.5f * gh;
            gw = fmaxf(gw, 1.f);
            gh = fmaxf(gh, 1.f);
            contrib_reg = smooth_l1((gcy - acy) / ah - r0) +
                          smooth_l1((gcx - acx) / aw - r1) +
                          smooth_l1(logf(gh / ah) - r2) +
                          smooth_l1(logf(gw / aw) - r3);

            atomicAdd(&s_cnt[bj], 1.f);
            atomicAdd(&s_sx[bj], e0);
            atomicAdd(&s_sy[bj], e1);
            atomicAdd(&s_sz[bj], e2);
            atomicAdd(&s_sq[bj], e0 * e0 + e1 * e1 + e2 * e2);
        }
    }
    __syncthreads();

    // ---------------- phase 2: coalesced focal sweep ----------------
    // C % 4 == 0 ==> a float4 never crosses an anchor boundary: ONE mask per float4.
    {
        const float4* tile = (const float4*)(cls + ((size_t)b * A + a0) * (size_t)C);
        float acc = 0.f;                     // sum of m * p^2 * log(1-p)  (negated later)
        if (a0 + 256 <= A && C == 80) {
            // full tile: compile-time trip count (20) -> unrolled, loads in flight
            #pragma unroll 5
            for (int k = 0; k < 20; k++) {
                const int e4 = tid + 256 * k;
                const float m = s_maskf[(unsigned)e4 / 20u];   // float4s per anchor = 20
                const float4 v = tile[e4];
                float p, l, s = 0.f;
                p = fminf(fmaxf(v.x, CLS_LO), CLS_HI); l = __logf(1.f - p); s = fmaf(p * p, l, s);
                p = fminf(fmaxf(v.y, CLS_LO), CLS_HI); l = __logf(1.f - p); s = fmaf(p * p, l, s);
                p = fminf(fmaxf(v.z, CLS_LO), CLS_HI); l = __logf(1.f - p); s = fmaf(p * p, l, s);
                p = fminf(fmaxf(v.w, CLS_LO), CLS_HI); l = __logf(1.f - p); s = fmaf(p * p, l, s);
                acc = fmaf(m, s, acc);
            }
        } else {
            const int nA   = min(256, A - a0);
            const int cpa4 = C >> 2;
            const int n4   = nA * cpa4;
            for (int e4 = tid; e4 < n4; e4 += 256) {
                const float m = s_maskf[(unsigned)e4 / (unsigned)cpa4];
                const float4 v = tile[e4];
                float p, l, s = 0.f;
                p = fminf(fmaxf(v.x, CLS_LO), CLS_HI); l = __logf(1.f - p); s = fmaf(p * p, l, s);
                p = fminf(fmaxf(v.y, CLS_LO), CLS_HI); l = __logf(1.f - p); s = fmaf(p * p, l, s);
                p = fminf(fmaxf(v.z, CLS_LO), CLS_HI); l = __logf(1.f - p); s = fmaf(p * p, l, s);
                p = fminf(fmaxf(v.w, CLS_LO), CLS_HI); l = __logf(1.f - p); s = fmaf(p * p, l, s);
                acc = fmaf(m, s, acc);
            }
        }
        contrib_cls -= 0.75f * acc;          // neg focal = 0.75 * p^2 * (-log(1-p))
    }

    // block-level reduction, then PLAIN stores to this block's private slot
    for (int off = 32; off > 0; off >>= 1) {
        contrib_cls += __shfl_down(contrib_cls, off, 64);
        contrib_reg += __shfl_down(contrib_reg, off, 64);
        contrib_np  += __shfl_down(contrib_np,  off, 64);
    }
    __shared__ float s_part[4][3];
    if ((tid & 63) == 0) {
        s_part[tid >> 6][0] = contrib_cls;
        s_part[tid >> 6][1] = contrib_reg;
        s_part[tid >> 6][2] = contrib_np;
    }
    __syncthreads();

    float* wsb = ws + (size_t)b * S;
    if (tid < M) {
        const float c = s_cnt[tid];
        if (c != 0.f) {   // only blocks containing positive anchors hit global atomics
            atomicAdd(&wsb[tid], c);
            atomicAdd(&wsb[M + 3 * tid + 0], s_sx[tid]);
            atomicAdd(&wsb[M + 3 * tid + 1], s_sy[tid]);
            atomicAdd(&wsb[M + 3 * tid + 2], s_sz[tid]);
            atomicAdd(&wsb[4 * M + tid], s_sq[tid]);
        }
    }
    if (tid == 0) {
        float* slot = wsb + 5 * M + 3 * blockIdx.x;
        slot[0] = s_part[0][0] + s_part[1][0] + s_part[2][0] + s_part[3][0];
        slot[1] = s_part[0][1] + s_part[1][1] + s_part[2][1] + s_part[3][1];
        slot[2] = s_part[0][2] + s_part[1][2] + s_part[2][2] + s_part[3][2];
    }
}

__global__ void __launch_bounds__(256)
det_final_kernel(const float* __restrict__ ws,
                 float* __restrict__ out,
                 int B, int M, int NB)
{
    const int t = threadIdx.x;
    const int S = 5 * M + 3 * NB;
    __shared__ float s_scal[8][3];
    __shared__ float s_emb[8];
    __shared__ float tmp[4][3];
    if (t < B) s_emb[t] = 0.f;

    for (int b = 0; b < B; b++) {
        const float* slots = ws + (size_t)b * S + 5 * M;
        float c = 0.f, r = 0.f, n = 0.f;
        for (int i = t; i < NB; i += 256) {
            c += slots[3 * i + 0];
            r += slots[3 * i + 1];
            n += slots[3 * i + 2];
        }
        for (int off = 32; off > 0; off >>= 1) {
            c += __shfl_down(c, off, 64);
            r += __shfl_down(r, off, 64);
            n += __shfl_down(n, off, 64);
        }
        if ((t & 63) == 0) { tmp[t >> 6][0] = c; tmp[t >> 6][1] = r; tmp[t >> 6][2] = n; }
        __syncthreads();
        if (t == 0) {
            s_scal[b][0] = tmp[0][0] + tmp[1][0] + tmp[2][0] + tmp[3][0];
            s_scal[b][1] = tmp[0][1] + tmp[1][1] + tmp[2][1] + tmp[3][1];
            s_scal[b][2] = tmp[0][2] + tmp[1][2] + tmp[2][2] + tmp[3][2];
        }
        __syncthreads();
    }

    if (t < B * M) {
        const int b = t / M;
        const int m = t - b * M;
        const float* wsb = ws + (size_t)b * S;
        const float c = wsb[m];
        float mx = 0.f, my = 0.f, mz = 0.f, pa = 0.f;
        if (c > 0.f) {
            mx = wsb[M + 3 * m + 0] / c;
            my = wsb[M + 3 * m + 1] / c;
            mz = wsb[M + 3 * m + 2] / c;
            // sum |e - mean|^2 = sum|e|^2 - c*|mean|^2
            const float sq = wsb[4 * M + m] - c * (mx * mx + my * my + mz * mz);
            pa = sq / fmaxf(c * 3.f, 1.f);
        }
        out[3 + (size_t)(b * M + m) * 3 + 0] = mx;
        out[3 + (size_t)(b * M + m) * 3 + 1] = my;
        out[3 + (size_t)(b * M + m) * 3 + 2] = mz;
        atomicAdd(&s_emb[b], pa);
    }
    __syncthreads();

    if (t == 0) {
        float cl = 0.f, rl = 0.f, el = 0.f;
        for (int b = 0; b < B; b++) {
            const float np = s_scal[b][2];
            cl += s_scal[b][0] / fmaxf(np, 1.f);
            rl += s_scal[b][1] / fmaxf(4.f * np, 1.f);
            el += s_emb[b] / (float)M;
        }
        const float invB = 1.f / (float)B;
        out[0] = cl * invB;
        out[1] = rl * invB * 50.f;
        out[2] = el * invB;
    }
}

extern "C" void kernel_launch(void* const* d_in, const int* in_sizes, int n_in,
                              void* d_out, int out_size, void* d_ws, size_t ws_size,
                              hipStream_t stream) {
    const float* cls = (const float*)d_in[0];
    const float* reg = (const float*)d_in[1];
    const float* anc = (const float*)d_in[2];
    const float* ann = (const float*)d_in[3];
    float* out = (float*)d_out;
    float* ws  = (float*)d_ws;

    const int A = in_sizes[2] / 4;               // anchors: (1, A, 4)
    const int B = in_sizes[1] / (A * 7);         // regressions: (B, A, 7)
    const int C = in_sizes[0] / (B * A);         // classifications: (B, A, C)
    const int M = in_sizes[3] / (B * 5);         // annotations: (B, M, 5)
    const int NB = (A + 255) / 256;
    const int S  = 5 * M + 3 * NB;

    hipMemsetAsync(ws, 0, (size_t)B * S * sizeof(float), stream);

    dim3 grid(NB, B);
    det_main_kernel<<<grid, 256, 0, stream>>>(cls, reg, anc, ann, ws, A, C, M, NB);
    det_final_kernel<<<1, 256, 0, stream>>>(ws, out, B, M, NB);
}